// Round 15
// baseline (2318.599 us; speedup 1.0000x reference)
//
#include <hip/hip_runtime.h>
#include <hip/hip_fp16.h>

#define NPART 131072
#define QDIM 32
#define DDIM 64
#define HDIM 50
#define STEPS 16
#define DT 0.1f
#define LN_EPS 1e-5f
#define INV_H 0.02f   // 1/50
#define ODIM 65       // output row stride

// ---- ws weight tables (4-byte units; f16 pairs over the contracted dim,
//      rows padded to 32 pairs so each half-lane reads exactly 4 uint4) ----
#define WS_W1TH 0      // u32 [50][32] pairs over d (64)
#define WS_W2TH 1600   // u32 [50][32] pairs over h (pad 64)
#define WS_UTH  3200   // u32 [50][32]
#define WS_MH   4800   // u32 [50][32]
#define WS_W3H  6400   // u32 [50][16] pairs over i (32)
#define WS_JV   7200   // f32 [50][4] {g2, be2, b2, sv}
#define WS_HV   7400   // f32 [64][4] {b1, g1, be1, 0}
#define WS_TOT  7656

// LDS: slots f32[50][128] + W2T,UT u32 tables + HV f32[64][4]
#define LT_W2T  6400   // u32 index into lds-as-u32
#define LT_UT   8000
#define LT_HV   9600   // f32 index
#define LDS_FLOATS 9856   // 39.4 KB

typedef float f4a __attribute__((ext_vector_type(4)));
typedef float f4u __attribute__((ext_vector_type(4), aligned(4)));
typedef unsigned int u32;
typedef _Float16 h2f __attribute__((ext_vector_type(2)));

__device__ __forceinline__ h2f as_h2(u32 x) { h2f r; __builtin_memcpy(&r, &x, 4); return r; }
__device__ __forceinline__ u32 h2_bits(h2f p) { u32 r; __builtin_memcpy(&r, &p, 4); return r; }
__device__ __forceinline__ u32 h2bits(float a, float b) {
    h2f p; p[0] = (_Float16)a; p[1] = (_Float16)b;
    u32 r; __builtin_memcpy(&r, &p, 4); return r;
}
__device__ __forceinline__ h2f mk_h2(float a, float b) {
    h2f p; p[0] = (_Float16)a; p[1] = (_Float16)b; return p;
}

#if __has_builtin(__builtin_amdgcn_fdot2)
#define FDOT2(a, b, c) __builtin_amdgcn_fdot2((a), (b), (c), false)
#else
#define FDOT2(a, b, c) ((float)(a)[0] * (float)(b)[0] + ((float)(a)[1] * (float)(b)[1] + (c)))
#endif

// ---------------- setup: padded split-friendly tables ----------------
__global__ void ode2vae_setup(const float* __restrict__ W1,
                              const float* __restrict__ W2,
                              const float* __restrict__ W3,
                              const float* __restrict__ b1, const float* __restrict__ g1,
                              const float* __restrict__ be1,
                              const float* __restrict__ b2, const float* __restrict__ g2,
                              const float* __restrict__ be2,
                              float* __restrict__ ws)
{
    const int tid = threadIdx.x;
    u32* wsu = (u32*)ws;
    for (int i = tid; i < WS_TOT; i += 256) wsu[i] = 0u;
    __syncthreads();
    // W1TH [50][32] pairs over d
    for (int idx = tid; idx < HDIM * 32; idx += 256) {
        const int h = idx >> 5, k = idx & 31, d = 2 * k;
        wsu[WS_W1TH + idx] = h2bits(W1[d * HDIM + h], W1[(d + 1) * HDIM + h]);
    }
    // W2TH / UTH / MH [50][32] pairs over h (pad h>=50 with zeros)
    for (int idx = tid; idx < HDIM * 32; idx += 256) {
        const int j = idx >> 5, k = idx & 31;
        float w2p[2], up[2], mp[2];
        #pragma unroll
        for (int t2 = 0; t2 < 2; ++t2) {
            const int h = 2 * k + t2;
            if (h < HDIM) {
                float u = 0.f;
                #pragma unroll
                for (int i = 0; i < QDIM; ++i)
                    u = fmaf(W1[i * HDIM + h], W3[j * QDIM + i], u);
                const float w2 = W2[h * HDIM + j];
                float rs = 0.f;
                for (int jj = 0; jj < HDIM; ++jj) rs += W2[h * HDIM + jj];
                w2p[t2] = w2; up[t2] = u; mp[t2] = u * (w2 - INV_H * rs);
            } else { w2p[t2] = 0.f; up[t2] = 0.f; mp[t2] = 0.f; }
        }
        wsu[WS_W2TH + idx] = h2bits(w2p[0], w2p[1]);
        wsu[WS_UTH  + idx] = h2bits(up[0], up[1]);
        wsu[WS_MH   + idx] = h2bits(mp[0], mp[1]);
    }
    // W3H [50][16] pairs over i
    for (int idx = tid; idx < HDIM * 16; idx += 256) {
        const int j = idx >> 4, k = idx & 15;
        wsu[WS_W3H + idx] = h2bits(W3[j * QDIM + 2 * k], W3[j * QDIM + 2 * k + 1]);
    }
    if (tid < HDIM) {
        float acc = 0.f;
        #pragma unroll
        for (int i = 0; i < QDIM; ++i) {
            float rs1 = 0.f;
            for (int h = 0; h < HDIM; ++h) rs1 += W1[i * HDIM + h];
            acc = fmaf(rs1, W3[tid * QDIM + i], acc);
        }
        ws[WS_JV + tid * 4 + 0] = g2[tid];
        ws[WS_JV + tid * 4 + 1] = be2[tid];
        ws[WS_JV + tid * 4 + 2] = b2[tid];
        ws[WS_JV + tid * 4 + 3] = acc;
        ws[WS_HV + tid * 4 + 0] = b1[tid];
        ws[WS_HV + tid * 4 + 1] = g1[tid];
        ws[WS_HV + tid * 4 + 2] = be1[tid];
        ws[WS_HV + tid * 4 + 3] = 0.f;
    }
    // HV rows 50..63 remain zero from the memset
}

// ---- half-row primitives (4 uint4 = 16 f16-pairs) ----
#define LD4(RB, SRC) { const uint4* S_ = (const uint4*)(SRC); \
    _Pragma("unroll") for (int c_ = 0; c_ < 4; ++c_) RB[c_] = S_[c_]; }
#define LD2(RB, SRC) { const uint4* S_ = (const uint4*)(SRC); \
    _Pragma("unroll") for (int c_ = 0; c_ < 2; ++c_) RB[c_] = S_[c_]; }

#define DOT16F(res, RB, P) { float q0=0.f,q1=0.f,q2=0.f,q3=0.f; \
    _Pragma("unroll") for (int c_ = 0; c_ < 4; ++c_) { const uint4 u_ = RB[c_]; \
        q0 = FDOT2(as_h2(u_.x), (P)[4*c_+0], q0); \
        q1 = FDOT2(as_h2(u_.y), (P)[4*c_+1], q1); \
        q2 = FDOT2(as_h2(u_.z), (P)[4*c_+2], q2); \
        q3 = FDOT2(as_h2(u_.w), (P)[4*c_+3], q3); } \
    res = (q0 + q1) + (q2 + q3); }

#define PKDOT16(res, RB, P) { h2f a0 = mk_h2(0.f,0.f), a1_ = a0; \
    _Pragma("unroll") for (int c_ = 0; c_ < 4; ++c_) { \
        a0  = as_h2(RB[c_].x) * (P)[4*c_+0] + a0; \
        a1_ = as_h2(RB[c_].y) * (P)[4*c_+1] + a1_; \
        a0  = as_h2(RB[c_].z) * (P)[4*c_+2] + a0; \
        a1_ = as_h2(RB[c_].w) * (P)[4*c_+3] + a1_; } \
    a0 = a0 + a1_; res = (float)a0[0] + (float)a0[1]; }

#define PKDOT_SAX16(res, RB, PA, ys, D) { h2f a0 = mk_h2(0.f,0.f), a1_ = a0; \
    _Pragma("unroll") for (int c_ = 0; c_ < 4; ++c_) { \
        const h2f x_ = as_h2(RB[c_].x), y_ = as_h2(RB[c_].y); \
        const h2f z_ = as_h2(RB[c_].z), w_ = as_h2(RB[c_].w); \
        a0  = x_ * (PA)[4*c_+0] + a0; (D)[4*c_+0] = x_ * (ys) + (D)[4*c_+0]; \
        a1_ = y_ * (PA)[4*c_+1] + a1_;(D)[4*c_+1] = y_ * (ys) + (D)[4*c_+1]; \
        a0  = z_ * (PA)[4*c_+2] + a0; (D)[4*c_+2] = z_ * (ys) + (D)[4*c_+2]; \
        a1_ = w_ * (PA)[4*c_+3] + a1_;(D)[4*c_+3] = w_ * (ys) + (D)[4*c_+3]; } \
    a0 = a0 + a1_; res = (float)a0[0] + (float)a0[1]; }

#define PK2DOT_SAX16(rA, rB_, RB, PA, PB, xs, D) { h2f aA = mk_h2(0.f,0.f), aB = aA; \
    _Pragma("unroll") for (int c_ = 0; c_ < 4; ++c_) { \
        const h2f x_ = as_h2(RB[c_].x), y_ = as_h2(RB[c_].y); \
        const h2f z_ = as_h2(RB[c_].z), w_ = as_h2(RB[c_].w); \
        aA = x_ * (PA)[4*c_+0] + aA; aB = x_ * (PB)[4*c_+0] + aB; \
        (D)[4*c_+0] = x_ * (xs) + (D)[4*c_+0]; \
        aA = y_ * (PA)[4*c_+1] + aA; aB = y_ * (PB)[4*c_+1] + aB; \
        (D)[4*c_+1] = y_ * (xs) + (D)[4*c_+1]; \
        aA = z_ * (PA)[4*c_+2] + aA; aB = z_ * (PB)[4*c_+2] + aB; \
        (D)[4*c_+2] = z_ * (xs) + (D)[4*c_+2]; \
        aA = w_ * (PA)[4*c_+3] + aA; aB = w_ * (PB)[4*c_+3] + aB; \
        (D)[4*c_+3] = w_ * (xs) + (D)[4*c_+3]; } \
    rA = (float)aA[0] + (float)aA[1]; rB_ = (float)aB[0] + (float)aB[1]; }

#define SAXPY8(RB, sh, D) { _Pragma("unroll") for (int c_ = 0; c_ < 2; ++c_) { \
        (D)[4*c_+0] = as_h2(RB[c_].x) * (sh) + (D)[4*c_+0]; \
        (D)[4*c_+1] = as_h2(RB[c_].y) * (sh) + (D)[4*c_+1]; \
        (D)[4*c_+2] = as_h2(RB[c_].z) * (sh) + (D)[4*c_+2]; \
        (D)[4*c_+3] = as_h2(RB[c_].w) * (sh) + (D)[4*c_+3]; } }

// 2 lanes per particle: lane parity = contraction half.
__global__ __launch_bounds__(256, 2)
void ode2vae_main(const float* __restrict__ z0, const float* __restrict__ logp0,
                  const float* __restrict__ b3,
                  const float* __restrict__ wsc,
                  float* out)                 // we read our own writes
{
    __shared__ float lds[LDS_FLOATS];
    const int tid = threadIdx.x;
    const int par = tid & 1;                  // contraction half
    const int pid = tid >> 1;                 // particle within block (0..127)
    const int n = blockIdx.x * 128 + pid;

    // stage W2T, UT, HV
    {
        const u32* src = (const u32*)wsc;
        u32* ldsu = (u32*)lds;
        for (int i = tid; i < 1600; i += 256) ldsu[LT_W2T + i] = src[WS_W2TH + i];
        for (int i = tid; i < 1600; i += 256) ldsu[LT_UT + i]  = src[WS_UTH + i];
        if (tid < 256) lds[LT_HV + tid] = wsc[WS_HV + tid];
    }
    __syncthreads();

    float* const SL = lds + pid;              // slot h at SL[h*128] (pair-shared)
    const u32* LW2T = (const u32*)lds + LT_W2T;
    const u32* LUT  = (const u32*)lds + LT_UT;
    const f4a* LHV  = (const f4a*)(lds + LT_HV);
    const u32* GW1  = (const u32*)wsc + WS_W1TH;   // per-lane half -> VMEM, L1-hot
    const u32* GM   = (const u32*)wsc + WS_MH;
    const u32* GW3  = (const u32*)wsc + WS_W3H;
    const f4a* GJV  = (const f4a*)(wsc + WS_JV);   // loop-uniform -> s_load

    float lp = logp0[n];
    const float* const zrow0 = z0 + (size_t)n * DDIM;
    const int hbase = par * 32;

    for (int s = 0; s < STEPS; ++s) {
        float* const odst = out + ((size_t)s * NPART + (size_t)n) * ODIM;
        const float* const zprev = (s == 0) ? zrow0
            : (out + ((size_t)(s - 1) * NPART + (size_t)n) * ODIM);

        // ======== A: my z-half f32 -> f16 pairs; 50 half-dots + combine ========
        h2f zh[16];
        {
            const float* zsrc = zprev + par * QDIM;
            #pragma unroll
            for (int k = 0; k < 8; ++k) {
                f4u v = *(const f4u*)(zsrc + 4 * k);
                zh[2*k]     = mk_h2(v[0], v[1]);
                zh[2*k + 1] = mk_h2(v[2], v[3]);
            }
        }
        float m1a = 0.f, v1a = 0.f;
        #pragma unroll 1
        for (int h = 0; h < HDIM; ++h) {
            uint4 RB[4];
            LD4(RB, GW1 + h * 32 + par * 16);
            float half;
            DOT16F(half, RB, zh);
            float a1h = half + __shfl_xor(half, 1, 64);
            a1h += LHV[h][0];                          // b1 (uniform LDS broadcast)
            if (par == 0) SL[h * 128] = a1h;
            m1a += a1h;
            v1a = fmaf(a1h, a1h, v1a);
        }
        const float m1 = m1a * INV_H;
        float var1 = v1a * INV_H - m1 * m1;
        var1 = var1 > 0.f ? var1 : 0.f;
        const float r1 = rsqrtf(var1 + LN_EPS);

        // ======== B+G: lane-local h-half (pads zero) ========
        h2f xh1p[16], hhp[16], w1vp[16], w1xp[16];
        #pragma unroll
        for (int hp = 0; hp < 16; ++hp) {
            const int h0 = hbase + 2 * hp;
            float xa = 0.f, xb = 0.f, ca = 0.f, cb = 0.f, wa = 0.f, wb = 0.f;
            if (h0 < HDIM) {
                const float aa = SL[h0 * 128];
                const float ab = SL[h0 * 128 + 128];
                const f4a hva = LHV[h0], hvb = LHV[h0 + 1];
                xa = (aa - m1) * r1; xb = (ab - m1) * r1;
                const float ya = fmaf(xa, hva[1], hva[2]);
                const float yb = fmaf(xb, hvb[1], hvb[2]);
                const float ea = __expf(ya), eb = __expf(yb);
                ca = (ya > 0.f) ? ya : (ea - 1.f);
                cb = (yb > 0.f) ? yb : (eb - 1.f);
                wa = ((ya > 0.f) ? 1.f : ea) * (hva[1] * r1);
                wb = ((yb > 0.f) ? 1.f : eb) * (hvb[1] * r1);
            }
            xh1p[hp] = mk_h2(xa, xb);
            hhp[hp]  = mk_h2(ca, cb);
            w1vp[hp] = mk_h2(wa, wb);
            w1xp[hp] = mk_h2(wa * xa, wb * xb);
        }

        // ======== C: a2 half-dots (LDS W2T half-rows) + combine ========
        float m2a = 0.f, v2a = 0.f;
        #pragma unroll 1
        for (int j = 0; j < HDIM; ++j) {
            uint4 RB[4];
            LD4(RB, LW2T + j * 32 + par * 16);
            float half;
            DOT16F(half, RB, hhp);
            float a2 = half + __shfl_xor(half, 1, 64);
            a2 += GJV[j][2];
            if (par == 0) SL[j * 128] = a2;
            m2a += a2;
            v2a = fmaf(a2, a2, v2a);
        }
        const float m2 = m2a * INV_H;
        float var2 = v2a * INV_H - m2 * m2;
        var2 = var2 > 0.f ? var2 : 0.f;
        const float r2 = rsqrtf(var2 + LN_EPS);

        // ======== FUSED j-pass: half-dots + per-j combines ========
        h2f duyp[16], php[16], dvp[8];
        #pragma unroll
        for (int k = 0; k < 16; ++k) { duyp[k] = mk_h2(0.f, 0.f); php[k] = mk_h2(0.f, 0.f); }
        #pragma unroll
        for (int k = 0; k < 8; ++k) dvp[k] = mk_h2(0.f, 0.f);
        float suA = 0.f, syA = 0.f, tuA = 0.f, tyA = 0.f;
        float A2a = 0.f, A2b = 0.f, A2c = 0.f;
        float A3a = 0.f, A3b = 0.f, A3c = 0.f;
        float T1A = 0.f;
        #pragma unroll 1
        for (int j = 0; j < HDIM; ++j) {
            const float x2 = (SL[j * 128] - m2) * r2;
            const f4a jv = GJV[j];
            const float y = fmaf(x2, jv[0], jv[1]);
            const float e = __expf(y);
            const float w2vj = ((y > 0.f) ? 1.f : e) * (jv[0] * r2);
            const float h2v = (y > 0.f) ? y : (e - 1.f);
            const float y3 = x2 * w2vj;

            uint4 RU[4];
            LD4(RU, LUT + j * 32 + par * 16);
            const h2f y3h = mk_h2(y3, y3);
            float tH;
            PKDOT_SAX16(tH, RU, xh1p, y3h, duyp);
            const float t = tH + __shfl_xor(tH, 1, 64);

            uint4 RW[4];
            LD4(RW, LW2T + j * 32 + par * 16);
            const h2f x2h = mk_h2(x2, x2);
            float c2H, c3H;
            PK2DOT_SAX16(c2H, c3H, RW, w1vp, w1xp, x2h, php);
            const float cS2 = c2H + __shfl_xor(c2H, 1, 64);
            const float cS3 = c3H + __shfl_xor(c3H, 1, 64);

            uint4 RM[4];
            LD4(RM, GM + j * 32 + par * 16);
            float cTH;
            PKDOT16(cTH, RM, w1vp);
            const float cTA = cTH + __shfl_xor(cTH, 1, 64);

            uint4 R3[2];
            LD2(R3, GW3 + j * 16 + par * 8);
            const h2f hb = mk_h2(h2v, h2v);
            SAXPY8(R3, hb, dvp);

            const float svw = jv[3] * w2vj;
            const float tw  = w2vj * t;
            suA += svw; syA = fmaf(svw, x2, syA);
            tuA += tw;  tyA = fmaf(tw, x2, tyA);
            A2a = fmaf(svw, cS2, A2a); A2b += cS2; A2c = fmaf(x2, cS2, A2c);
            A3a = fmaf(tw,  cS3, A3a); A3b += cS3; A3c = fmaf(x2, cS3, A3c);
            T1A = fmaf(w2vj, cTA, T1A);
        }

        // ======== epilogue ========
        float T1cH;
        {
            h2f acc0 = mk_h2(0.f, 0.f), acc1 = acc0;
            #pragma unroll
            for (int k = 0; k < 16; k += 2) {
                acc0 = (w1vp[k] * duyp[k]) * php[k] + acc0;
                acc1 = (w1vp[k+1] * duyp[k+1]) * php[k+1] + acc1;
            }
            acc0 = acc0 + acc1;
            T1cH = (float)acc0[0] + (float)acc0[1];
        }
        const float T1c = T1cH + __shfl_xor(T1cH, 1, 64);
        const float suH = suA * INV_H, syH = syA * INV_H;
        const float tuH = tuA * INV_H, tyH = tyA * INV_H;
        const float S2 = A2a - suH * A2b - syH * A2c;
        const float S3 = A3a - tuH * A3b - tyH * A3c;
        const float tr = T1A - (T1c + S2 + S3) * INV_H;
        lp = fmaf(-DT, tr, lp);

        // exchange partner's dv half (all lanes execute the shfl)
        u32 odvb[8];
        #pragma unroll
        for (int k = 0; k < 8; ++k) odvb[k] = __shfl_xor(h2_bits(dvp[k]), 1, 64);

        if (par == 0) {
            // zq_new = zq_old + DT*(dv + b3); store odst[0..31], lp
            #pragma unroll
            for (int k = 0; k < 8; ++k) {
                f4u q = *(const f4u*)(zprev + 4 * k);
                h2f dA_, dB_;
                if (k < 4) { dA_ = dvp[2*k]; dB_ = dvp[2*k + 1]; }
                else       { dA_ = as_h2(odvb[2*(k-4)]); dB_ = as_h2(odvb[2*(k-4) + 1]); }
                f4u o;
                o[0] = fmaf(DT, (float)dA_[0] + b3[4*k + 0], q[0]);
                o[1] = fmaf(DT, (float)dA_[1] + b3[4*k + 1], q[1]);
                o[2] = fmaf(DT, (float)dB_[0] + b3[4*k + 2], q[2]);
                o[3] = fmaf(DT, (float)dB_[1] + b3[4*k + 3], q[3]);
                *(f4u*)(odst + 4 * k) = o;
            }
            odst[DDIM] = lp;
        } else {
            // zs_new = zs_old + DT*zq_old; store odst[32..63]
            #pragma unroll
            for (int k = 0; k < 8; ++k) {
                f4u q  = *(const f4u*)(zprev + 4 * k);
                f4u sv = *(const f4u*)(zprev + QDIM + 4 * k);
                f4u o;
                o[0] = fmaf(DT, q[0], sv[0]);
                o[1] = fmaf(DT, q[1], sv[1]);
                o[2] = fmaf(DT, q[2], sv[2]);
                o[3] = fmaf(DT, q[3], sv[3]);
                *(f4u*)(odst + QDIM + 4 * k) = o;
            }
        }
    }
}

extern "C" void kernel_launch(void* const* d_in, const int* in_sizes, int n_in,
                              void* d_out, int out_size, void* d_ws, size_t ws_size,
                              hipStream_t stream)
{
    const float* z0    = (const float*)d_in[0];
    const float* logp0 = (const float*)d_in[1];
    const float* W1    = (const float*)d_in[2];
    const float* b1    = (const float*)d_in[3];
    const float* g1    = (const float*)d_in[4];
    const float* be1   = (const float*)d_in[5];
    const float* W2    = (const float*)d_in[6];
    const float* b2    = (const float*)d_in[7];
    const float* g2    = (const float*)d_in[8];
    const float* be2   = (const float*)d_in[9];
    const float* W3    = (const float*)d_in[10];
    const float* b3    = (const float*)d_in[11];
    float* out = (float*)d_out;
    float* ws  = (float*)d_ws;

    hipLaunchKernelGGL(ode2vae_setup, dim3(1), dim3(256), 0, stream,
                       W1, W2, W3, b1, g1, be1, b2, g2, be2, ws);
    hipLaunchKernelGGL(ode2vae_main, dim3(NPART / 128), dim3(256), 0, stream,
                       z0, logp0, b3, ws, out);
}

// Round 16
// 1355.041 us; speedup vs baseline: 1.7111x; 1.7111x over previous
//
#include <hip/hip_runtime.h>
#include <hip/hip_fp16.h>

#define NPART 131072
#define QDIM 32
#define DDIM 64
#define HDIM 50
#define STEPS 16
#define DT 0.1f
#define LN_EPS 1e-5f
#define INV_H 0.02f   // 1/50
#define ODIM 65       // output row stride

// ---- ws weight tables (u32 units; f16 pairs over the contracted dim) ----
#define WS_W1TH 0      // [50][32]  pairs over d (64)
#define WS_W2TH 1600   // [50][28]  pairs over h (50, pad 56)
#define WS_UTH  3000   // [50][28]
#define WS_MH   4400   // [50][28]
#define WS_W3H  5800   // [50][16]  pairs over i (32)
#define WS_JV   6600   // f32 [50][4] {g2, be2, b2, sv}
#define WS_HV   6800   // f32 [50][4] {b1, g1, be1, 0}
#define WS_TOT  7000   // 28000 B

// LDS-resident tables: W2TH + UTH (2800 u32 = 11.2 KB)
#define LT_W2TH 0
#define LT_UTH  1400
#define LT_TOT  2800

#define SLOT_FLOATS (HDIM * 256)              // 12800 floats = 51.2 KB
#define LDS_FLOATS  (SLOT_FLOATS + LT_TOT)    // 15600 floats = 62.4 KB

typedef float f4a __attribute__((ext_vector_type(4)));
typedef float f4u __attribute__((ext_vector_type(4), aligned(4)));
typedef unsigned int u32;
typedef _Float16 h2f __attribute__((ext_vector_type(2)));

__device__ __forceinline__ h2f as_h2(u32 x) { h2f r; __builtin_memcpy(&r, &x, 4); return r; }
__device__ __forceinline__ u32 h2bits(float a, float b) {
    h2f p; p[0] = (_Float16)a; p[1] = (_Float16)b;
    u32 r; __builtin_memcpy(&r, &p, 4); return r;
}
__device__ __forceinline__ h2f mk_h2(float a, float b) {
    h2f p; p[0] = (_Float16)a; p[1] = (_Float16)b; return p;
}

#if __has_builtin(__builtin_amdgcn_fdot2)
#define FDOT2(a, b, c) __builtin_amdgcn_fdot2((a), (b), (c), false)
#else
#define FDOT2(a, b, c) ((float)(a)[0] * (float)(b)[0] + ((float)(a)[1] * (float)(b)[1] + (c)))
#endif

// ---- f16 x2/tw pair in an f32 slot ----
__device__ __forceinline__ float pack2h(float x, float t) {
    u32 r = h2bits(x, t); float f; __builtin_memcpy(&f, &r, 4); return f;
}
__device__ __forceinline__ void unpack2h(float f, float& x, float& t) {
    u32 u; __builtin_memcpy(&u, &f, 4); h2f p = as_h2(u); x = (float)p[0]; t = (float)p[1];
}

// ---------------- setup ----------------
__global__ void ode2vae_setup(const float* __restrict__ W1,
                              const float* __restrict__ W2,
                              const float* __restrict__ W3,
                              const float* __restrict__ b1, const float* __restrict__ g1,
                              const float* __restrict__ be1,
                              const float* __restrict__ b2, const float* __restrict__ g2,
                              const float* __restrict__ be2,
                              float* __restrict__ ws)
{
    const int tid = threadIdx.x;
    u32* wsu = (u32*)ws;
    for (int i = tid; i < WS_TOT; i += 256) wsu[i] = 0u;
    __syncthreads();
    for (int idx = tid; idx < HDIM * 32; idx += 256) {
        const int h = idx / 32, k = idx % 32;
        wsu[WS_W1TH + h * 32 + k] = h2bits(W1[(2 * k) * HDIM + h], W1[(2 * k + 1) * HDIM + h]);
    }
    for (int idx = tid; idx < HDIM * 25; idx += 256) {
        const int j = idx / 25, k = idx % 25;
        float w2p[2], up[2], mp[2];
        #pragma unroll
        for (int s_ = 0; s_ < 2; ++s_) {
            const int h = 2 * k + s_;
            float u = 0.f;
            #pragma unroll
            for (int i = 0; i < QDIM; ++i)
                u = fmaf(W1[i * HDIM + h], W3[j * QDIM + i], u);
            const float w2 = W2[h * HDIM + j];
            float rs = 0.f;
            for (int jj = 0; jj < HDIM; ++jj) rs += W2[h * HDIM + jj];
            w2p[s_] = w2; up[s_] = u; mp[s_] = u * (w2 - INV_H * rs);
        }
        wsu[WS_W2TH + j * 28 + k] = h2bits(w2p[0], w2p[1]);
        wsu[WS_UTH  + j * 28 + k] = h2bits(up[0], up[1]);
        wsu[WS_MH   + j * 28 + k] = h2bits(mp[0], mp[1]);
    }
    for (int idx = tid; idx < HDIM * 16; idx += 256) {
        const int j = idx / 16, k = idx % 16;
        wsu[WS_W3H + j * 16 + k] = h2bits(W3[j * QDIM + 2 * k], W3[j * QDIM + 2 * k + 1]);
    }
    if (tid < HDIM) {
        float acc = 0.f;
        #pragma unroll
        for (int i = 0; i < QDIM; ++i) {
            float rs1 = 0.f;
            for (int h = 0; h < HDIM; ++h) rs1 += W1[i * HDIM + h];
            acc = fmaf(rs1, W3[tid * QDIM + i], acc);
        }
        ws[WS_JV + tid * 4 + 0] = g2[tid];
        ws[WS_JV + tid * 4 + 1] = be2[tid];
        ws[WS_JV + tid * 4 + 2] = b2[tid];
        ws[WS_JV + tid * 4 + 3] = acc;
        ws[WS_HV + tid * 4 + 0] = b1[tid];
        ws[WS_HV + tid * 4 + 1] = g1[tid];
        ws[WS_HV + tid * 4 + 2] = be1[tid];
        ws[WS_HV + tid * 4 + 3] = 0.f;
    }
}

// ---- forward dots (f32 accumulate) ----
#define DOT64(res, rowp, P)                                           \
    {                                                                 \
        float q0 = 0.f, q1 = 0.f, q2 = 0.f, q3 = 0.f;                 \
        const uint4* R_ = (const uint4*)(rowp);                       \
        _Pragma("unroll")                                             \
        for (int c_ = 0; c_ < 8; ++c_) {                              \
            const uint4 u_ = R_[c_];                                  \
            q0 = FDOT2(as_h2(u_.x), (P)[4*c_ + 0], q0);               \
            q1 = FDOT2(as_h2(u_.y), (P)[4*c_ + 1], q1);               \
            q2 = FDOT2(as_h2(u_.z), (P)[4*c_ + 2], q2);               \
            q3 = FDOT2(as_h2(u_.w), (P)[4*c_ + 3], q3);               \
        }                                                             \
        res = (q0 + q1) + (q2 + q3);                                  \
    }
#define DOT56(res, rowp, P)                                           \
    {                                                                 \
        float q0 = 0.f, q1 = 0.f, q2 = 0.f, q3 = 0.f;                 \
        const uint4* R_ = (const uint4*)(rowp);                       \
        _Pragma("unroll")                                             \
        for (int c_ = 0; c_ < 7; ++c_) {                              \
            const uint4 u_ = R_[c_];                                  \
            q0 = FDOT2(as_h2(u_.x), (P)[4*c_ + 0], q0);               \
            q1 = FDOT2(as_h2(u_.y), (P)[4*c_ + 1], q1);               \
            q2 = FDOT2(as_h2(u_.z), (P)[4*c_ + 2], q2);               \
            q3 = FDOT2(as_h2(u_.w), (P)[4*c_ + 3], q3);               \
        }                                                             \
        res = (q0 + q1) + (q2 + q3);                                  \
    }

// ---- trace dots: pure packed-f16 (v_pk_fma_f16) ----
#define LDROW7(RB, SRC) { const uint4* S_ = (const uint4*)(SRC);      \
    _Pragma("unroll") for (int c_ = 0; c_ < 7; ++c_) RB[c_] = S_[c_]; }
#define LDROW4(RB, SRC) { const uint4* S_ = (const uint4*)(SRC);      \
    _Pragma("unroll") for (int c_ = 0; c_ < 4; ++c_) RB[c_] = S_[c_]; }

#define PKDOT_RB(res, RB, P)                                          \
    {                                                                 \
        h2f a0 = mk_h2(0.f, 0.f), a1_ = a0;                           \
        _Pragma("unroll")                                             \
        for (int c_ = 0; c_ < 7; ++c_) {                              \
            a0  = as_h2(RB[c_].x) * (P)[4*c_ + 0] + a0;               \
            a1_ = as_h2(RB[c_].y) * (P)[4*c_ + 1] + a1_;              \
            a0  = as_h2(RB[c_].z) * (P)[4*c_ + 2] + a0;               \
            a1_ = as_h2(RB[c_].w) * (P)[4*c_ + 3] + a1_;              \
        }                                                             \
        a0 = a0 + a1_;                                                \
        res = (float)a0[0] + (float)a0[1];                            \
    }

#define PKDOT_SAX_RB(res, RB, PA, ys, D)                              \
    {                                                                 \
        h2f a0 = mk_h2(0.f, 0.f), a1_ = a0;                           \
        _Pragma("unroll")                                             \
        for (int c_ = 0; c_ < 7; ++c_) {                              \
            const h2f x_ = as_h2(RB[c_].x), y_ = as_h2(RB[c_].y);     \
            const h2f z_ = as_h2(RB[c_].z), w_ = as_h2(RB[c_].w);     \
            a0  = x_ * (PA)[4*c_ + 0] + a0;                           \
            (D)[4*c_ + 0] = x_ * (ys) + (D)[4*c_ + 0];                \
            a1_ = y_ * (PA)[4*c_ + 1] + a1_;                          \
            (D)[4*c_ + 1] = y_ * (ys) + (D)[4*c_ + 1];                \
            a0  = z_ * (PA)[4*c_ + 2] + a0;                           \
            (D)[4*c_ + 2] = z_ * (ys) + (D)[4*c_ + 2];                \
            a1_ = w_ * (PA)[4*c_ + 3] + a1_;                          \
            (D)[4*c_ + 3] = w_ * (ys) + (D)[4*c_ + 3];                \
        }                                                             \
        a0 = a0 + a1_;                                                \
        res = (float)a0[0] + (float)a0[1];                            \
    }

#define PK2DOT_SAX_RB(rA, rB, RB, PA, PB, xs, D)                      \
    {                                                                 \
        h2f aA = mk_h2(0.f, 0.f), aB = aA;                            \
        _Pragma("unroll")                                             \
        for (int c_ = 0; c_ < 7; ++c_) {                              \
            const h2f x_ = as_h2(RB[c_].x), y_ = as_h2(RB[c_].y);     \
            const h2f z_ = as_h2(RB[c_].z), w_ = as_h2(RB[c_].w);     \
            aA = x_ * (PA)[4*c_ + 0] + aA;                            \
            aB = x_ * (PB)[4*c_ + 0] + aB;                            \
            (D)[4*c_ + 0] = x_ * (xs) + (D)[4*c_ + 0];                \
            aA = y_ * (PA)[4*c_ + 1] + aA;                            \
            aB = y_ * (PB)[4*c_ + 1] + aB;                            \
            (D)[4*c_ + 1] = y_ * (xs) + (D)[4*c_ + 1];                \
            aA = z_ * (PA)[4*c_ + 2] + aA;                            \
            aB = z_ * (PB)[4*c_ + 2] + aB;                            \
            (D)[4*c_ + 2] = z_ * (xs) + (D)[4*c_ + 2];                \
            aA = w_ * (PA)[4*c_ + 3] + aA;                            \
            aB = w_ * (PB)[4*c_ + 3] + aB;                            \
            (D)[4*c_ + 3] = w_ * (xs) + (D)[4*c_ + 3];                \
        }                                                             \
        rA = (float)aA[0] + (float)aA[1];                             \
        rB = (float)aB[0] + (float)aB[1];                             \
    }

#define SAXPY_RB4(RB, sh, D)                                          \
    {                                                                 \
        _Pragma("unroll")                                             \
        for (int c_ = 0; c_ < 4; ++c_) {                              \
            (D)[4*c_ + 0] = as_h2(RB[c_].x) * (sh) + (D)[4*c_ + 0];   \
            (D)[4*c_ + 1] = as_h2(RB[c_].y) * (sh) + (D)[4*c_ + 1];   \
            (D)[4*c_ + 2] = as_h2(RB[c_].z) * (sh) + (D)[4*c_ + 2];   \
            (D)[4*c_ + 3] = as_h2(RB[c_].w) * (sh) + (D)[4*c_ + 3];   \
        }                                                             \
    }

__global__ __launch_bounds__(256, 2)
void ode2vae_main(const float* __restrict__ z0, const float* __restrict__ logp0,
                  const float* __restrict__ b3,
                  const float* __restrict__ wsc,  // const + uniform idx -> s_load
                  float* out)                     // we read our own writes
{
    __shared__ float lds[LDS_FLOATS];
    const int tid = threadIdx.x;
    const int n = blockIdx.x * 256 + tid;

    // stage only W2TH + UTH into LDS
    {
        const u32* src = (const u32*)wsc;
        u32* dst = (u32*)(lds + SLOT_FLOATS);
        for (int i = tid; i < 1400; i += 256) dst[LT_W2TH + i] = src[WS_W2TH + i];
        for (int i = tid; i < 1400; i += 256) dst[LT_UTH + i]  = src[WS_UTH + i];
    }
    __syncthreads();

    float* const L = lds + tid;                         // slot k at L[k*256]
    const u32* LW2TH = (const u32*)(lds + SLOT_FLOATS) + LT_W2TH;
    const u32* LUTH  = (const u32*)(lds + SLOT_FLOATS) + LT_UTH;
    // scalar-pipe tables (global, uniform address -> s_load, K$-cached)
    const u32* GW1TH = (const u32*)wsc + WS_W1TH;
    const u32* GMH   = (const u32*)wsc + WS_MH;
    const u32* GW3H  = (const u32*)wsc + WS_W3H;
    const f4a* GJV   = (const f4a*)(wsc + WS_JV);
    const f4a* GHV   = (const f4a*)(wsc + WS_HV);

    float lp = logp0[n];
    const float* const zrow0 = z0 + (size_t)n * DDIM;

    for (int s = 0; s < STEPS; ++s) {
        float* const odst = out + ((size_t)s * NPART + (size_t)n) * ODIM;
        const float* const zprev = (s == 0) ? zrow0
            : (out + ((size_t)(s - 1) * NPART + (size_t)n) * ODIM);

        // ======== A: load z (both halves), pack; a1 rows via SCALAR W1T ========
        float zq[QDIM], zs[QDIM];
        #pragma unroll
        for (int k = 0; k < 8; ++k) {
            f4u v = *(const f4u*)(zprev + 4 * k);
            zq[4*k] = v[0]; zq[4*k+1] = v[1]; zq[4*k+2] = v[2]; zq[4*k+3] = v[3];
        }
        #pragma unroll
        for (int k = 0; k < 8; ++k) {
            f4u v = *(const f4u*)(zprev + QDIM + 4 * k);
            zs[4*k] = v[0]; zs[4*k+1] = v[1]; zs[4*k+2] = v[2]; zs[4*k+3] = v[3];
        }
        h2f zp[32];
        #pragma unroll
        for (int k = 0; k < 16; ++k) zp[k] = mk_h2(zq[2*k], zq[2*k+1]);
        #pragma unroll
        for (int k = 0; k < 16; ++k) zp[16 + k] = mk_h2(zs[2*k], zs[2*k+1]);

        float m1a = 0.f, v1a = 0.f;
        #pragma unroll 1
        for (int h = 0; h < HDIM; ++h) {
            float a1h;
            DOT64(a1h, GW1TH + h * 32, zp);
            const f4a hv = GHV[h];
            a1h += hv[0];
            L[h * 256] = a1h;
            m1a += a1h;
            v1a = fmaf(a1h, a1h, v1a);
        }
        // zs_new = zs + DT*zq (old zq); store; z regs die
        #pragma unroll
        for (int k = 0; k < QDIM; ++k) zs[k] = fmaf(DT, zq[k], zs[k]);
        #pragma unroll
        for (int k = 0; k < 8; ++k) {
            f4u v = {zs[4*k], zs[4*k+1], zs[4*k+2], zs[4*k+3]};
            *(f4u*)(odst + QDIM + 4 * k) = v;
        }
        const float m1 = m1a * INV_H;
        float var1 = v1a * INV_H - m1 * m1;
        var1 = var1 > 0.f ? var1 : 0.f;
        const float r1 = rsqrtf(var1 + LN_EPS);

        // ======== B+G: xh1p, hhp, w1vp, w1xp ========
        h2f xh1p[28], hhp[28], w1vp[28], w1xp[28];
        #pragma unroll
        for (int hp = 0; hp < 25; ++hp) {
            const float xa = (L[(2*hp) * 256] - m1) * r1;
            const float xb = (L[(2*hp + 1) * 256] - m1) * r1;
            const f4a hva = GHV[2*hp], hvb = GHV[2*hp + 1];
            const float ya = fmaf(xa, hva[1], hva[2]);
            const float yb = fmaf(xb, hvb[1], hvb[2]);
            const float ea = __expf(ya), eb = __expf(yb);
            const float ca = (ya > 0.f) ? ya : (ea - 1.f);
            const float cb = (yb > 0.f) ? yb : (eb - 1.f);
            const float wa = ((ya > 0.f) ? 1.f : ea) * (hva[1] * r1);
            const float wb = ((yb > 0.f) ? 1.f : eb) * (hvb[1] * r1);
            xh1p[hp] = mk_h2(xa, xb);
            hhp[hp]  = mk_h2(ca, cb);
            w1vp[hp] = mk_h2(wa, wb);
            w1xp[hp] = mk_h2(wa * xa, wb * xb);
        }
        #pragma unroll
        for (int hp = 25; hp < 28; ++hp) {
            xh1p[hp] = mk_h2(0.f, 0.f); hhp[hp] = mk_h2(0.f, 0.f);
            w1vp[hp] = mk_h2(0.f, 0.f); w1xp[hp] = mk_h2(0.f, 0.f);
        }

        // ======== C: a2 -> slots (f32 acc, LDS W2T rows) ========
        float m2a = 0.f, v2a = 0.f;
        #pragma unroll 1
        for (int j = 0; j < HDIM; ++j) {
            float a2j;
            DOT56(a2j, LW2TH + j * 28, hhp);
            const f4a jv = GJV[j];
            a2j += jv[2];
            L[j * 256] = a2j;
            m2a += a2j;
            v2a = fmaf(a2j, a2j, v2a);
        }
        const float m2 = m2a * INV_H;
        float var2 = v2a * INV_H - m2 * m2;
        var2 = var2 > 0.f ? var2 : 0.f;
        const float r2 = rsqrtf(var2 + LN_EPS);

        // ======== FUSED j-pass: every weight row read ONCE ========
        h2f duyp[28], php[28];
        #pragma unroll
        for (int k = 0; k < 28; ++k) { duyp[k] = mk_h2(0.f, 0.f); php[k] = mk_h2(0.f, 0.f); }
        h2f dvp[16];
        #pragma unroll
        for (int k = 0; k < 16; ++k) dvp[k] = mk_h2(0.f, 0.f);
        float suA = 0.f, syA = 0.f, tuA = 0.f, tyA = 0.f;
        float A2a = 0.f, A2b = 0.f, A2c = 0.f;
        float A3a = 0.f, A3b = 0.f, A3c = 0.f;
        float T1A = 0.f;
        #pragma unroll 1
        for (int j = 0; j < HDIM; ++j) {
            const float x2 = (L[j * 256] - m2) * r2;
            const f4a jv = GJV[j];
            const float y = fmaf(x2, jv[0], jv[1]);
            const float e = __expf(y);
            const float w2vj = ((y > 0.f) ? 1.f : e) * (jv[0] * r2);
            const float h2v = (y > 0.f) ? y : (e - 1.f);

            // UT row: t-dot (xh1p) + duy saxpy (y3)
            uint4 RU[7];
            LDROW7(RU, LUTH + j * 28);
            const float y3 = x2 * w2vj;
            const h2f y3h = mk_h2(y3, y3);
            float t;
            PKDOT_SAX_RB(t, RU, xh1p, y3h, duyp);

            // W2T row: cS2 (w1v), cS3 (w1x), php saxpy (x2)
            uint4 RW[7];
            LDROW7(RW, LW2TH + j * 28);
            const h2f x2h = mk_h2(x2, x2);
            float cS2, cS3;
            PK2DOT_SAX_RB(cS2, cS3, RW, w1vp, w1xp, x2h, php);

            // M row (scalar): cTA dot (w1v)
            uint4 RM[7];
            LDROW7(RM, GMH + j * 28);
            float cTA;
            PKDOT_RB(cTA, RM, w1vp);

            // W3 row (scalar): dv saxpy (h2)
            uint4 R3[4];
            LDROW4(R3, GW3H + j * 16);
            const h2f hb = mk_h2(h2v, h2v);
            SAXPY_RB4(R3, hb, dvp);

            // scalar accumulators
            const float svw = jv[3] * w2vj;
            const float tw  = w2vj * t;
            suA += svw; syA = fmaf(svw, x2, syA);
            tuA += tw;  tyA = fmaf(tw, x2, tyA);
            A2a = fmaf(svw, cS2, A2a); A2b += cS2; A2c = fmaf(x2, cS2, A2c);
            A3a = fmaf(tw,  cS3, A3a); A3b += cS3; A3c = fmaf(x2, cS3, A3c);
            T1A = fmaf(w2vj, cTA, T1A);
        }

        // ======== epilogue: reload zq early; assemble trace; update; store ====
        float zq2[QDIM];
        #pragma unroll
        for (int k = 0; k < 8; ++k) {
            f4u v = *(const f4u*)(zprev + 4 * k);
            zq2[4*k] = v[0]; zq2[4*k+1] = v[1]; zq2[4*k+2] = v[2]; zq2[4*k+3] = v[3];
        }

        const float suH = suA * INV_H, syH = syA * INV_H;
        const float tuH = tuA * INV_H, tyH = tyA * INV_H;
        const float S2 = A2a - suH * A2b - syH * A2c;
        const float S3 = A3a - tuH * A3b - tyH * A3c;
        // T1c = sum_h w1v*duy*ph
        float T1c;
        {
            h2f acc0 = mk_h2(0.f, 0.f), acc1 = acc0;
            #pragma unroll
            for (int k = 0; k < 28; k += 2) {
                acc0 = (w1vp[k] * duyp[k]) * php[k] + acc0;
                acc1 = (w1vp[k+1] * duyp[k+1]) * php[k+1] + acc1;
            }
            acc0 = acc0 + acc1;
            T1c = (float)acc0[0] + (float)acc0[1];
        }
        const float tr = T1A - (T1c + S2 + S3) * INV_H;

        lp = fmaf(-DT, tr, lp);
        #pragma unroll
        for (int k = 0; k < 16; ++k) {
            const float da = (float)dvp[k][0] + b3[2*k];
            const float db = (float)dvp[k][1] + b3[2*k + 1];
            zq2[2*k]     = fmaf(DT, da, zq2[2*k]);
            zq2[2*k + 1] = fmaf(DT, db, zq2[2*k + 1]);
        }
        #pragma unroll
        for (int k = 0; k < 8; ++k) {
            f4u v = {zq2[4*k], zq2[4*k+1], zq2[4*k+2], zq2[4*k+3]};
            *(f4u*)(odst + 4 * k) = v;
        }
        odst[DDIM] = lp;
    }
}

extern "C" void kernel_launch(void* const* d_in, const int* in_sizes, int n_in,
                              void* d_out, int out_size, void* d_ws, size_t ws_size,
                              hipStream_t stream)
{
    const float* z0    = (const float*)d_in[0];
    const float* logp0 = (const float*)d_in[1];
    const float* W1    = (const float*)d_in[2];
    const float* b1    = (const float*)d_in[3];
    const float* g1    = (const float*)d_in[4];
    const float* be1   = (const float*)d_in[5];
    const float* W2    = (const float*)d_in[6];
    const float* b2    = (const float*)d_in[7];
    const float* g2    = (const float*)d_in[8];
    const float* be2   = (const float*)d_in[9];
    const float* W3    = (const float*)d_in[10];
    const float* b3    = (const float*)d_in[11];
    float* out = (float*)d_out;
    float* ws  = (float*)d_ws;

    hipLaunchKernelGGL(ode2vae_setup, dim3(1), dim3(256), 0, stream,
                       W1, W2, W3, b1, g1, be1, b2, g2, be2, ws);
    hipLaunchKernelGGL(ode2vae_main, dim3(NPART / 256), dim3(256), 0, stream,
                       z0, logp0, b3, ws, out);
}